// Round 1
// baseline (1235.848 us; speedup 1.0000x reference)
//
#include <hip/hip_runtime.h>

// VocabParallelEmbeddingWithDelta: out[t,:] = weight[x[t],:] + (indices[t] >= 0
//   ? delta_weights[indices[t], x[t], :] : 0)
// T=8192 tokens, D=2048, fp32. Pure memory-bound double gather + add.
// One 256-thread block per token; float4 (16B/lane) fully-coalesced row copies.

#define EMBED 2048
#define VOCAB 32000
#define CHUNKS (EMBED / 4)   // 512 float4 per row

__global__ __launch_bounds__(256)
void VocabParallelEmbeddingWithDelta_28973849379098_kernel(
        const int* __restrict__ x,
        const int* __restrict__ indices,
        const float* __restrict__ weight,
        const float* __restrict__ delta_weights,
        float* __restrict__ out) {
    const int token = blockIdx.x;
    const int tok_id = x[token];        // wave-uniform (same addr all lanes)
    const int adapter = indices[token]; // wave-uniform

    const float4* __restrict__ wrow =
        (const float4*)(weight + (size_t)tok_id * EMBED);
    float4* __restrict__ orow = (float4*)(out + (size_t)token * EMBED);

    if (adapter >= 0) {
        const float4* __restrict__ drow =
            (const float4*)(delta_weights +
                            ((size_t)adapter * VOCAB + (size_t)tok_id) * EMBED);
        // 512 chunks / 256 threads = 2 iterations; unrolled for ILP.
        #pragma unroll
        for (int i = 0; i < 2; ++i) {
            const int c = threadIdx.x + i * 256;
            float4 w = wrow[c];
            float4 d = drow[c];
            w.x += d.x; w.y += d.y; w.z += d.z; w.w += d.w;
            orow[c] = w;
        }
    } else {
        #pragma unroll
        for (int i = 0; i < 2; ++i) {
            const int c = threadIdx.x + i * 256;
            orow[c] = wrow[c];
        }
    }
}

extern "C" void kernel_launch(void* const* d_in, const int* in_sizes, int n_in,
                              void* d_out, int out_size, void* d_ws, size_t ws_size,
                              hipStream_t stream) {
    const int*   x             = (const int*)d_in[0];
    const int*   indices       = (const int*)d_in[1];
    const float* weight        = (const float*)d_in[2];
    const float* delta_weights = (const float*)d_in[3];
    float*       out           = (float*)d_out;

    const int num_tokens = in_sizes[0];  // 8192

    VocabParallelEmbeddingWithDelta_28973849379098_kernel
        <<<num_tokens, 256, 0, stream>>>(x, indices, weight, delta_weights, out);
}